// Round 10
// baseline (92.460 us; speedup 1.0000x reference)
//
#include <hip/hip_runtime.h>
#include <hip/hip_fp16.h>

#define DIN 1024
#define H_SZ 512
#define OUT_SZ 512
#define EPSF 1e-8f

typedef __attribute__((ext_vector_type(8))) short short8v;   // 8 bf16 = 4 VGPRs
typedef __attribute__((ext_vector_type(4))) float f32x4;
typedef _Float16 half2v __attribute__((ext_vector_type(2)));

// fp32 -> bf16 (RNE)
static __device__ inline unsigned short f2bf(float f) {
    unsigned u = __float_as_uint(f);
    u = u + 0x7FFFu + ((u >> 16) & 1u);
    return (unsigned short)(u >> 16);
}

// Canberra core: 6 packed ops per 2 terms (proven rounds 3/5/6/8/9, absmax 1.5e-5).
static __device__ inline void canb2(unsigned hu, unsigned wu, unsigned& a, unsigned two) {
    unsigned mn, sm, tt, y;
    asm("v_pk_min_f16 %0, %1, %2" : "=v"(mn) : "v"(hu), "v"(wu));
    asm("v_pk_add_f16 %0, %1, %2" : "=v"(sm) : "v"(hu), "v"(wu));
    y = 0x77847784u - sm;                           // magic rcp seed (v_sub_u32)
    asm("v_pk_fma_f16 %0, %1, %2, %3 neg_lo:[1,0,0] neg_hi:[1,0,0]"
        : "=v"(tt) : "v"(sm), "v"(y), "v"(two));    // tt = 2 - sm*y
    asm("v_pk_mul_f16 %0, %1, %2" : "=v"(y) : "v"(y), "v"(tt));
    asm("v_pk_fma_f16 %0, %1, %2, %0" : "+v"(a) : "v"(mn), "v"(y));
}

// ---------------- GEMM (r8-proven, byte-identical to r9) ----------------
__global__ __launch_bounds__(512, 4) void gemm8(const float* __restrict__ x,
                                                const float* __restrict__ W1,
                                                const float* __restrict__ b1,
                                                const float* __restrict__ Wd,
                                                unsigned short* __restrict__ hh,
                                                unsigned short* __restrict__ wh) {
    __shared__ unsigned short As[2][2][32][72];   // [khalf][buf][m][k]
    __shared__ unsigned short Bs[2][2][32][72];
    __shared__ float red[4][64][4];
    const int t  = threadIdx.x;
    const int b0 = blockIdx.x * 32;
    const int o0 = blockIdx.y * 32;

    const int w  = t >> 6;
    const int l  = t & 63;
    const int q  = w & 3;
    const int kh = w >> 2;
    const int m0 = (q >> 1) * 16;
    const int n0 = (q & 1) * 16;
    const int lr = l & 15;
    const int lk = (l >> 4) * 8;
    const int th = t & 255;
    const int ar = th >> 3;
    const int ko = (th & 7) * 8;

    f32x4 acc = {0.f, 0.f, 0.f, 0.f};
    const float* arow = &x [(size_t)(b0 + ar) * DIN + kh * 512 + ko];
    const float* brow = &W1[(size_t)(o0 + ar) * DIN + kh * 512 + ko];
    float4 pa0 = *reinterpret_cast<const float4*>(arow);
    float4 pa1 = *reinterpret_cast<const float4*>(arow + 4);
    float4 pb0 = *reinterpret_cast<const float4*>(brow);
    float4 pb1 = *reinterpret_cast<const float4*>(brow + 4);

    for (int k0 = 0; k0 < 512; k0 += 64) {
        const int buf = (k0 >> 6) & 1;
        short8v av, bv;
        av[0] = (short)f2bf(pa0.x); av[1] = (short)f2bf(pa0.y);
        av[2] = (short)f2bf(pa0.z); av[3] = (short)f2bf(pa0.w);
        av[4] = (short)f2bf(pa1.x); av[5] = (short)f2bf(pa1.y);
        av[6] = (short)f2bf(pa1.z); av[7] = (short)f2bf(pa1.w);
        bv[0] = (short)f2bf(pb0.x); bv[1] = (short)f2bf(pb0.y);
        bv[2] = (short)f2bf(pb0.z); bv[3] = (short)f2bf(pb0.w);
        bv[4] = (short)f2bf(pb1.x); bv[5] = (short)f2bf(pb1.y);
        bv[6] = (short)f2bf(pb1.z); bv[7] = (short)f2bf(pb1.w);
        *reinterpret_cast<short8v*>(&As[kh][buf][ar][ko]) = av;
        *reinterpret_cast<short8v*>(&Bs[kh][buf][ar][ko]) = bv;
        __syncthreads();   // dbuf safe: buf^1's last reads were 2 syncs back (proven r5-r9)
        if (k0 + 64 < 512) {
            pa0 = *reinterpret_cast<const float4*>(arow + k0 + 64);
            pa1 = *reinterpret_cast<const float4*>(arow + k0 + 68);
            pb0 = *reinterpret_cast<const float4*>(brow + k0 + 64);
            pb1 = *reinterpret_cast<const float4*>(brow + k0 + 68);
        }
        #pragma unroll
        for (int s = 0; s < 2; ++s) {
            const short8v af = *reinterpret_cast<const short8v*>(&As[kh][buf][m0 + lr][s * 32 + lk]);
            const short8v bf = *reinterpret_cast<const short8v*>(&Bs[kh][buf][n0 + lr][s * 32 + lk]);
            acc = __builtin_amdgcn_mfma_f32_16x16x32_bf16(af, bf, acc, 0, 0, 0);
        }
    }
    __syncthreads();
    if (kh == 1) {
        #pragma unroll
        for (int r = 0; r < 4; ++r) red[q][l][r] = acc[r];
    }
    __syncthreads();
    if (kh == 0) {
        // C/D layout (m89-verified): col = lane&15, row = (lane>>4)*4 + reg
        const int col = o0 + n0 + lr;
        const float bias = b1[col];
        #pragma unroll
        for (int r = 0; r < 4; ++r) {
            const float v = acc[r] + red[q][l][r] + bias;
            const int m = b0 + m0 + (l >> 4) * 4 + r;
            hh[(size_t)m * H_SZ + col] = __half_as_ushort(__float2half(fmaxf(v, 0.0f)));
        }
    }
    // Wd preprocess: 262144 elems == 512 blocks * 512 thr. +0 only (no -0 bits).
    const int gid = (blockIdx.y * 32 + blockIdx.x) * 512 + t;
    const float wv0 = Wd[gid];
    wh[gid] = __half_as_ushort(__float2half(wv0 > 0.f ? wv0 : 0.f));
}

// ---------------- Canberra (byte-identical to r9) ----------------
__global__ __launch_bounds__(512, 8) void canberra6(const unsigned short* __restrict__ hh,
                                                    const unsigned short* __restrict__ wh,
                                                    float* __restrict__ out) {
    __shared__ unsigned hs[32][132];   // 32 b-rows x 128 uints (256 k) + pad 4
    __shared__ unsigned ws[16][132];   // 16 o-rows x 128 uints + pad 4
    const int t  = threadIdx.x;
    const int b0 = blockIdx.x * 32;
    const int o0 = blockIdx.y * 16;
    const unsigned* hu = reinterpret_cast<const unsigned*>(hh);
    const unsigned* wu = reinterpret_cast<const unsigned*>(wh);

    const int ks = t >> 6;     // 0..7, wave-uniform k-slice
    const int l  = t & 63;
    const int bi = l >> 3;     // 0..7
    const int oj = l & 7;      // 0..7
    const unsigned two = 0x40004000u;   // {2.0h, 2.0h}

    unsigned acc[4][2] = {};

    for (int ch = 0; ch < 2; ++ch) {    // two 256-k chunks
        if (ch) __syncthreads();        // previous chunk's reads complete
        #pragma unroll
        for (int r = 0; r < 2; ++r) {
            const int s = t + r * 512;
            const int row = s >> 5;         // 0..31
            const int c4  = s & 31;         // uint4 col
            *reinterpret_cast<uint4*>(&hs[row][c4 * 4]) =
                *reinterpret_cast<const uint4*>(&hu[(size_t)(b0 + row) * 256 + ch * 128 + c4 * 4]);
        }
        {
            const int row = t >> 5;         // 0..15
            const int c4  = t & 31;
            *reinterpret_cast<uint4*>(&ws[row][c4 * 4]) =
                *reinterpret_cast<const uint4*>(&wu[(size_t)(o0 + row) * 256 + ch * 128 + c4 * 4]);
        }
        __syncthreads();

        #pragma unroll
        for (int g = 0; g < 4; ++g) {   // 4 uint4-cols = 32 k per thread per chunk
            const int col = ks * 16 + g * 4;
            uint4 hv[4], wv[2];
            #pragma unroll
            for (int c = 0; c < 4; ++c)
                hv[c] = *reinterpret_cast<const uint4*>(&hs[bi + 8 * c][col]);
            #pragma unroll
            for (int d = 0; d < 2; ++d)
                wv[d] = *reinterpret_cast<const uint4*>(&ws[oj + 8 * d][col]);
            #pragma unroll
            for (int c = 0; c < 4; ++c) {
                #pragma unroll
                for (int d = 0; d < 2; ++d) {
                    canb2(hv[c].x, wv[d].x, acc[c][d], two);
                    canb2(hv[c].y, wv[d].y, acc[c][d], two);
                    canb2(hv[c].z, wv[d].z, acc[c][d], two);
                    canb2(hv[c].w, wv[d].w, acc[c][d], two);
                }
            }
        }
    }

    float p[8];
    #pragma unroll
    for (int c = 0; c < 4; ++c)
        #pragma unroll
        for (int d = 0; d < 2; ++d) {
            const half2v av = __builtin_bit_cast(half2v, acc[c][d]);
            p[c * 2 + d] = (float)av.x + (float)av.y;
        }

    // 8-way k-reduce, transposed conflict-free layout (r8-proven): bank = lane%32
    __syncthreads();
    float* red = reinterpret_cast<float*>(&hs[0][0]);   // [8][448] floats = 14.3 KB
    if (ks > 0) {
        const int slot = (ks - 1) * 64 + l;
        #pragma unroll
        for (int i = 0; i < 8; ++i) red[i * 448 + slot] = p[i];
    }
    __syncthreads();
    if (ks == 0) {
        #pragma unroll
        for (int q = 0; q < 7; ++q) {
            #pragma unroll
            for (int i = 0; i < 8; ++i) p[i] += red[i * 448 + q * 64 + l];
        }
        #pragma unroll
        for (int c = 0; c < 4; ++c) {
            #pragma unroll
            for (int d = 0; d < 2; ++d) {
                float dd = 512.0f - 2.0f * p[c * 2 + d] + EPSF;
                dd = fminf(fmaxf(dd, EPSF), 1000000.0f);
                out[(size_t)(b0 + bi + 8 * c) * OUT_SZ + o0 + oj + 8 * d] = 1.0f / dd;
            }
        }
    }
}

extern "C" void kernel_launch(void* const* d_in, const int* in_sizes, int n_in,
                              void* d_out, int out_size, void* d_ws, size_t ws_size,
                              hipStream_t stream) {
    const float* x  = (const float*)d_in[0];
    const float* W1 = (const float*)d_in[1];
    const float* b1 = (const float*)d_in[2];
    const float* Wd = (const float*)d_in[3];
    float* out = (float*)d_out;
    unsigned short* hh = (unsigned short*)d_ws;                          // 1 MB fp16 h
    unsigned short* wh = (unsigned short*)((char*)d_ws + (1u << 20));    // 0.5 MB fp16 relu(Wd)

    // MEASUREMENT ROUND: canberra6 launched 3x (idempotent: identical inputs -> identical out;
    // deterministic; graph-safe). With r9 baseline g+c = 40.0 us and this T = g + 3c:
    //   c = (T - 40.0)/2,  g = 40.0 - c.
    // Resolves the gemm/canberra split that harness-fill occlusion has hidden since round 3.
    gemm8<<<dim3(32, 16), 512, 0, stream>>>(x, W1, b1, Wd, hh, wh);
    canberra6<<<dim3(32, 32), 512, 0, stream>>>(hh, wh, out);
    canberra6<<<dim3(32, 32), 512, 0, stream>>>(hh, wh, out);
    canberra6<<<dim3(32, 32), 512, 0, stream>>>(hh, wh, out);
}

// Round 11
// 40.272 us; speedup vs baseline: 2.2959x; 2.2959x over previous
//
#include <hip/hip_runtime.h>
#include <hip/hip_fp16.h>

#define DIN 1024
#define H_SZ 512
#define OUT_SZ 512
#define EPSF 1e-8f

typedef __attribute__((ext_vector_type(8))) short short8v;   // 8 bf16 = 4 VGPRs
typedef __attribute__((ext_vector_type(4))) float f32x4;
typedef _Float16 half2v __attribute__((ext_vector_type(2)));

// Canberra core: 6 packed ops per 2 terms (proven rounds 3/5/6/8/9, absmax 1.5e-5).
static __device__ inline void canb2(unsigned hu, unsigned wu, unsigned& a, unsigned two) {
    unsigned mn, sm, tt, y;
    asm("v_pk_min_f16 %0, %1, %2" : "=v"(mn) : "v"(hu), "v"(wu));
    asm("v_pk_add_f16 %0, %1, %2" : "=v"(sm) : "v"(hu), "v"(wu));
    y = 0x77847784u - sm;                           // magic rcp seed (v_sub_u32)
    asm("v_pk_fma_f16 %0, %1, %2, %3 neg_lo:[1,0,0] neg_hi:[1,0,0]"
        : "=v"(tt) : "v"(sm), "v"(y), "v"(two));    // tt = 2 - sm*y
    asm("v_pk_mul_f16 %0, %1, %2" : "=v"(y) : "v"(y), "v"(tt));
    asm("v_pk_fma_f16 %0, %1, %2, %0" : "+v"(a) : "v"(mn), "v"(y));
}

// pack 2 fp32 -> 2 bf16 in one op (gfx950; RNE)
static __device__ inline unsigned cvtpk(float lo, float hi) {
    unsigned u;
    asm("v_cvt_pk_bf16_f32 %0, %1, %2" : "=v"(u) : "v"(lo), "v"(hi));
    return u;
}

// ---------------- GEMM v9: depth-2 register prefetch + cvt_pk conversions ----------------
// Structure identical to r8-proven gemm8 (8 waves = 4 quadrants x 2 k-halves, BK=64 LDS dbuf,
// LDS accumulator exchange, folded Wd relu-cvt). Changes: (a) global loads issued 2 iters
// (2 barriers, ~500cyc) ahead of use; (b) f32->bf16 via v_cvt_pk_bf16_f32 (8 ops vs ~50).
__global__ __launch_bounds__(512, 4) void gemm9(const float* __restrict__ x,
                                                const float* __restrict__ W1,
                                                const float* __restrict__ b1,
                                                const float* __restrict__ Wd,
                                                unsigned short* __restrict__ hh,
                                                unsigned short* __restrict__ wh) {
    __shared__ unsigned short As[2][2][32][72];   // [khalf][buf][m][k]
    __shared__ unsigned short Bs[2][2][32][72];
    __shared__ float red[4][64][4];
    const int t  = threadIdx.x;
    const int b0 = blockIdx.x * 32;
    const int o0 = blockIdx.y * 32;

    const int w  = t >> 6;
    const int l  = t & 63;
    const int q  = w & 3;
    const int kh = w >> 2;             // k-half 0/1
    const int m0 = (q >> 1) * 16;
    const int n0 = (q & 1) * 16;
    const int lr = l & 15;
    const int lk = (l >> 4) * 8;
    const int th = t & 255;
    const int ar = th >> 3;            // 0..31
    const int ko = (th & 7) * 8;       // 0..56

    f32x4 acc = {0.f, 0.f, 0.f, 0.f};
    const float* arow = &x [(size_t)(b0 + ar) * DIN + kh * 512 + ko];
    const float* brow = &W1[(size_t)(o0 + ar) * DIN + kh * 512 + ko];

    float4 pa0[2], pa1[2], pb0[2], pb1[2];   // depth-2 prefetch ring (32 VGPR)
    #pragma unroll
    for (int i = 0; i < 2; ++i) {
        pa0[i] = *reinterpret_cast<const float4*>(arow + i * 64);
        pa1[i] = *reinterpret_cast<const float4*>(arow + i * 64 + 4);
        pb0[i] = *reinterpret_cast<const float4*>(brow + i * 64);
        pb1[i] = *reinterpret_cast<const float4*>(brow + i * 64 + 4);
    }

    #pragma unroll
    for (int it = 0; it < 8; ++it) {
        const int sl  = it & 1;        // reg ring slot == LDS dbuf
        uint4 av, bv;
        av.x = cvtpk(pa0[sl].x, pa0[sl].y);
        av.y = cvtpk(pa0[sl].z, pa0[sl].w);
        av.z = cvtpk(pa1[sl].x, pa1[sl].y);
        av.w = cvtpk(pa1[sl].z, pa1[sl].w);
        bv.x = cvtpk(pb0[sl].x, pb0[sl].y);
        bv.y = cvtpk(pb0[sl].z, pb0[sl].w);
        bv.z = cvtpk(pb1[sl].x, pb1[sl].y);
        bv.w = cvtpk(pb1[sl].z, pb1[sl].w);
        *reinterpret_cast<uint4*>(&As[kh][sl][ar][ko]) = av;
        *reinterpret_cast<uint4*>(&Bs[kh][sl][ar][ko]) = bv;
        __syncthreads();   // dbuf safe: buf^1's last reads were 1 sync back (proven r5-r10)
        if (it + 2 < 8) {  // prefetch 2 iters ahead into the slot just consumed
            pa0[sl] = *reinterpret_cast<const float4*>(arow + (it + 2) * 64);
            pa1[sl] = *reinterpret_cast<const float4*>(arow + (it + 2) * 64 + 4);
            pb0[sl] = *reinterpret_cast<const float4*>(brow + (it + 2) * 64);
            pb1[sl] = *reinterpret_cast<const float4*>(brow + (it + 2) * 64 + 4);
        }
        #pragma unroll
        for (int s = 0; s < 2; ++s) {
            const short8v af = *reinterpret_cast<const short8v*>(&As[kh][sl][m0 + lr][s * 32 + lk]);
            const short8v bf = *reinterpret_cast<const short8v*>(&Bs[kh][sl][n0 + lr][s * 32 + lk]);
            acc = __builtin_amdgcn_mfma_f32_16x16x32_bf16(af, bf, acc, 0, 0, 0);
        }
    }
    __syncthreads();
    if (kh == 1) {
        #pragma unroll
        for (int r = 0; r < 4; ++r) red[q][l][r] = acc[r];
    }
    __syncthreads();
    if (kh == 0) {
        // C/D layout (m89-verified): col = lane&15, row = (lane>>4)*4 + reg
        const int col = o0 + n0 + lr;
        const float bias = b1[col];
        #pragma unroll
        for (int r = 0; r < 4; ++r) {
            const float v = acc[r] + red[q][l][r] + bias;
            const int m = b0 + m0 + (l >> 4) * 4 + r;
            hh[(size_t)m * H_SZ + col] = __half_as_ushort(__float2half(fmaxf(v, 0.0f)));
        }
    }
    // Wd preprocess: 262144 elems == 512 blocks * 512 thr. +0 only (no -0 bits).
    const int gid = (blockIdx.y * 32 + blockIdx.x) * 512 + t;
    const float wv0 = Wd[gid];
    wh[gid] = __half_as_ushort(__float2half(wv0 > 0.f ? wv0 : 0.f));
}

// ---------------- Canberra (byte-identical to r9/r10 — at its VALU-issue floor) ----------------
__global__ __launch_bounds__(512, 8) void canberra6(const unsigned short* __restrict__ hh,
                                                    const unsigned short* __restrict__ wh,
                                                    float* __restrict__ out) {
    __shared__ unsigned hs[32][132];   // 32 b-rows x 128 uints (256 k) + pad 4
    __shared__ unsigned ws[16][132];   // 16 o-rows x 128 uints + pad 4
    const int t  = threadIdx.x;
    const int b0 = blockIdx.x * 32;
    const int o0 = blockIdx.y * 16;
    const unsigned* hu = reinterpret_cast<const unsigned*>(hh);
    const unsigned* wu = reinterpret_cast<const unsigned*>(wh);

    const int ks = t >> 6;     // 0..7, wave-uniform k-slice
    const int l  = t & 63;
    const int bi = l >> 3;     // 0..7
    const int oj = l & 7;      // 0..7
    const unsigned two = 0x40004000u;   // {2.0h, 2.0h}

    unsigned acc[4][2] = {};

    for (int ch = 0; ch < 2; ++ch) {    // two 256-k chunks
        if (ch) __syncthreads();        // previous chunk's reads complete
        #pragma unroll
        for (int r = 0; r < 2; ++r) {
            const int s = t + r * 512;
            const int row = s >> 5;         // 0..31
            const int c4  = s & 31;         // uint4 col
            *reinterpret_cast<uint4*>(&hs[row][c4 * 4]) =
                *reinterpret_cast<const uint4*>(&hu[(size_t)(b0 + row) * 256 + ch * 128 + c4 * 4]);
        }
        {
            const int row = t >> 5;         // 0..15
            const int c4  = t & 31;
            *reinterpret_cast<uint4*>(&ws[row][c4 * 4]) =
                *reinterpret_cast<const uint4*>(&wu[(size_t)(o0 + row) * 256 + ch * 128 + c4 * 4]);
        }
        __syncthreads();

        #pragma unroll
        for (int g = 0; g < 4; ++g) {   // 4 uint4-cols = 32 k per thread per chunk
            const int col = ks * 16 + g * 4;
            uint4 hv[4], wv[2];
            #pragma unroll
            for (int c = 0; c < 4; ++c)
                hv[c] = *reinterpret_cast<const uint4*>(&hs[bi + 8 * c][col]);
            #pragma unroll
            for (int d = 0; d < 2; ++d)
                wv[d] = *reinterpret_cast<const uint4*>(&ws[oj + 8 * d][col]);
            #pragma unroll
            for (int c = 0; c < 4; ++c) {
                #pragma unroll
                for (int d = 0; d < 2; ++d) {
                    canb2(hv[c].x, wv[d].x, acc[c][d], two);
                    canb2(hv[c].y, wv[d].y, acc[c][d], two);
                    canb2(hv[c].z, wv[d].z, acc[c][d], two);
                    canb2(hv[c].w, wv[d].w, acc[c][d], two);
                }
            }
        }
    }

    float p[8];
    #pragma unroll
    for (int c = 0; c < 4; ++c)
        #pragma unroll
        for (int d = 0; d < 2; ++d) {
            const half2v av = __builtin_bit_cast(half2v, acc[c][d]);
            p[c * 2 + d] = (float)av.x + (float)av.y;
        }

    // 8-way k-reduce, transposed conflict-free layout (r8-proven): bank = lane%32
    __syncthreads();
    float* red = reinterpret_cast<float*>(&hs[0][0]);   // [8][448] floats = 14.3 KB
    if (ks > 0) {
        const int slot = (ks - 1) * 64 + l;
        #pragma unroll
        for (int i = 0; i < 8; ++i) red[i * 448 + slot] = p[i];
    }
    __syncthreads();
    if (ks == 0) {
        #pragma unroll
        for (int q = 0; q < 7; ++q) {
            #pragma unroll
            for (int i = 0; i < 8; ++i) p[i] += red[i * 448 + q * 64 + l];
        }
        #pragma unroll
        for (int c = 0; c < 4; ++c) {
            #pragma unroll
            for (int d = 0; d < 2; ++d) {
                float dd = 512.0f - 2.0f * p[c * 2 + d] + EPSF;
                dd = fminf(fmaxf(dd, EPSF), 1000000.0f);
                out[(size_t)(b0 + bi + 8 * c) * OUT_SZ + o0 + oj + 8 * d] = 1.0f / dd;
            }
        }
    }
}

extern "C" void kernel_launch(void* const* d_in, const int* in_sizes, int n_in,
                              void* d_out, int out_size, void* d_ws, size_t ws_size,
                              hipStream_t stream) {
    const float* x  = (const float*)d_in[0];
    const float* W1 = (const float*)d_in[1];
    const float* b1 = (const float*)d_in[2];
    const float* Wd = (const float*)d_in[3];
    float* out = (float*)d_out;
    unsigned short* hh = (unsigned short*)d_ws;                          // 1 MB fp16 h
    unsigned short* wh = (unsigned short*)((char*)d_ws + (1u << 20));    // 0.5 MB fp16 relu(Wd)

    gemm9<<<dim3(32, 16), 512, 0, stream>>>(x, W1, b1, Wd, hh, wh);
    canberra6<<<dim3(32, 32), 512, 0, stream>>>(hh, wh, out);
}

// Round 12
// 39.242 us; speedup vs baseline: 2.3561x; 1.0263x over previous
//
#include <hip/hip_runtime.h>
#include <hip/hip_fp16.h>

#define DIN 1024
#define H_SZ 512
#define OUT_SZ 512
#define EPSF 1e-8f

typedef __attribute__((ext_vector_type(8))) short short8v;   // 8 bf16 = 4 VGPRs
typedef __attribute__((ext_vector_type(4))) float f32x4;
typedef _Float16 half2v __attribute__((ext_vector_type(2)));

// Canberra core: 6 packed ops per 2 terms (proven rounds 3/5/6/8-11, absmax 1.5e-5).
static __device__ inline void canb2(unsigned hu, unsigned wu, unsigned& a, unsigned two) {
    unsigned mn, sm, tt, y;
    asm("v_pk_min_f16 %0, %1, %2" : "=v"(mn) : "v"(hu), "v"(wu));
    asm("v_pk_add_f16 %0, %1, %2" : "=v"(sm) : "v"(hu), "v"(wu));
    y = 0x77847784u - sm;                           // magic rcp seed (v_sub_u32)
    asm("v_pk_fma_f16 %0, %1, %2, %3 neg_lo:[1,0,0] neg_hi:[1,0,0]"
        : "=v"(tt) : "v"(sm), "v"(y), "v"(two));    // tt = 2 - sm*y
    asm("v_pk_mul_f16 %0, %1, %2" : "=v"(y) : "v"(y), "v"(tt));
    asm("v_pk_fma_f16 %0, %1, %2, %0" : "+v"(a) : "v"(mn), "v"(y));
}

// pack 2 fp32 -> 2 bf16 in one op (gfx950; RNE)
static __device__ inline unsigned cvtpk(float lo, float hi) {
    unsigned u;
    asm("v_cvt_pk_bf16_f32 %0, %1, %2" : "=v"(u) : "v"(lo), "v"(hi));
    return u;
}

// ---------------- GEMM v10: r11 structure + XCD-quadrant swizzle (T1) ----------------
// Theory: 64 MB of redundant x/W1 reads were HBM-served because default round-robin
// (XCD = flat%8, m09) gives every XCD a ~6MB working set > 4MB L2. Remap so each XCD
// owns 8 b-tiles x 8 o-tiles: working set 2MB -> L2-resident; HBM drops to ~16MB.
__global__ __launch_bounds__(512, 4) void gemm10(const float* __restrict__ x,
                                                 const float* __restrict__ W1,
                                                 const float* __restrict__ b1,
                                                 const float* __restrict__ Wd,
                                                 unsigned short* __restrict__ hh,
                                                 unsigned short* __restrict__ wh) {
    __shared__ unsigned short As[2][2][32][72];   // [khalf][buf][m][k]
    __shared__ unsigned short Bs[2][2][32][72];
    __shared__ float red[4][64][4];
    const int t  = threadIdx.x;

    // bijective XCD swizzle: flat -> (xcd, idx) -> (b-tile, o-tile)
    const int flat = blockIdx.x + 32 * blockIdx.y;   // 0..511, dispatch order
    const int xcd  = flat & 7;
    const int idx  = flat >> 3;                      // 0..63 within XCD
    const int bt   = (xcd >> 1) * 8 + (idx & 7);     // b-tile 0..31
    const int ot   = (xcd & 1) * 8 + (idx >> 3);     // o-tile 0..15
    const int b0 = bt * 32;
    const int o0 = ot * 32;

    const int w  = t >> 6;
    const int l  = t & 63;
    const int q  = w & 3;
    const int kh = w >> 2;             // k-half 0/1
    const int m0 = (q >> 1) * 16;
    const int n0 = (q & 1) * 16;
    const int lr = l & 15;
    const int lk = (l >> 4) * 8;
    const int th = t & 255;
    const int ar = th >> 3;            // 0..31
    const int ko = (th & 7) * 8;       // 0..56

    f32x4 acc = {0.f, 0.f, 0.f, 0.f};
    const float* arow = &x [(size_t)(b0 + ar) * DIN + kh * 512 + ko];
    const float* brow = &W1[(size_t)(o0 + ar) * DIN + kh * 512 + ko];

    float4 pa0[2], pa1[2], pb0[2], pb1[2];   // depth-2 prefetch ring
    #pragma unroll
    for (int i = 0; i < 2; ++i) {
        pa0[i] = *reinterpret_cast<const float4*>(arow + i * 64);
        pa1[i] = *reinterpret_cast<const float4*>(arow + i * 64 + 4);
        pb0[i] = *reinterpret_cast<const float4*>(brow + i * 64);
        pb1[i] = *reinterpret_cast<const float4*>(brow + i * 64 + 4);
    }

    #pragma unroll
    for (int it = 0; it < 8; ++it) {
        const int sl  = it & 1;        // reg ring slot == LDS dbuf
        uint4 av, bv;
        av.x = cvtpk(pa0[sl].x, pa0[sl].y);
        av.y = cvtpk(pa0[sl].z, pa0[sl].w);
        av.z = cvtpk(pa1[sl].x, pa1[sl].y);
        av.w = cvtpk(pa1[sl].z, pa1[sl].w);
        bv.x = cvtpk(pb0[sl].x, pb0[sl].y);
        bv.y = cvtpk(pb0[sl].z, pb0[sl].w);
        bv.z = cvtpk(pb1[sl].x, pb1[sl].y);
        bv.w = cvtpk(pb1[sl].z, pb1[sl].w);
        *reinterpret_cast<uint4*>(&As[kh][sl][ar][ko]) = av;
        *reinterpret_cast<uint4*>(&Bs[kh][sl][ar][ko]) = bv;
        __syncthreads();   // dbuf safe (proven r5-r11)
        if (it + 2 < 8) {  // prefetch 2 iters ahead into the slot just consumed
            pa0[sl] = *reinterpret_cast<const float4*>(arow + (it + 2) * 64);
            pa1[sl] = *reinterpret_cast<const float4*>(arow + (it + 2) * 64 + 4);
            pb0[sl] = *reinterpret_cast<const float4*>(brow + (it + 2) * 64);
            pb1[sl] = *reinterpret_cast<const float4*>(brow + (it + 2) * 64 + 4);
        }
        #pragma unroll
        for (int s = 0; s < 2; ++s) {
            const short8v af = *reinterpret_cast<const short8v*>(&As[kh][sl][m0 + lr][s * 32 + lk]);
            const short8v bf = *reinterpret_cast<const short8v*>(&Bs[kh][sl][n0 + lr][s * 32 + lk]);
            acc = __builtin_amdgcn_mfma_f32_16x16x32_bf16(af, bf, acc, 0, 0, 0);
        }
    }
    __syncthreads();
    if (kh == 1) {
        #pragma unroll
        for (int r = 0; r < 4; ++r) red[q][l][r] = acc[r];
    }
    __syncthreads();
    if (kh == 0) {
        // C/D layout (m89-verified): col = lane&15, row = (lane>>4)*4 + reg
        const int col = o0 + n0 + lr;
        const float bias = b1[col];
        #pragma unroll
        for (int r = 0; r < 4; ++r) {
            const float v = acc[r] + red[q][l][r] + bias;
            const int m = b0 + m0 + (l >> 4) * 4 + r;
            hh[(size_t)m * H_SZ + col] = __half_as_ushort(__float2half(fmaxf(v, 0.0f)));
        }
    }
    // Wd preprocess: 262144 elems == 512 blocks * 512 thr (flat covers 0..511 bijectively).
    const int gid = flat * 512 + t;
    const float wv0 = Wd[gid];
    wh[gid] = __half_as_ushort(__float2half(wv0 > 0.f ? wv0 : 0.f));
}

// ---------------- Canberra (byte-identical to r9-r11 — at its VALU-issue floor) ----------------
__global__ __launch_bounds__(512, 8) void canberra6(const unsigned short* __restrict__ hh,
                                                    const unsigned short* __restrict__ wh,
                                                    float* __restrict__ out) {
    __shared__ unsigned hs[32][132];   // 32 b-rows x 128 uints (256 k) + pad 4
    __shared__ unsigned ws[16][132];   // 16 o-rows x 128 uints + pad 4
    const int t  = threadIdx.x;
    const int b0 = blockIdx.x * 32;
    const int o0 = blockIdx.y * 16;
    const unsigned* hu = reinterpret_cast<const unsigned*>(hh);
    const unsigned* wu = reinterpret_cast<const unsigned*>(wh);

    const int ks = t >> 6;     // 0..7, wave-uniform k-slice
    const int l  = t & 63;
    const int bi = l >> 3;     // 0..7
    const int oj = l & 7;      // 0..7
    const unsigned two = 0x40004000u;   // {2.0h, 2.0h}

    unsigned acc[4][2] = {};

    for (int ch = 0; ch < 2; ++ch) {    // two 256-k chunks
        if (ch) __syncthreads();        // previous chunk's reads complete
        #pragma unroll
        for (int r = 0; r < 2; ++r) {
            const int s = t + r * 512;
            const int row = s >> 5;         // 0..31
            const int c4  = s & 31;         // uint4 col
            *reinterpret_cast<uint4*>(&hs[row][c4 * 4]) =
                *reinterpret_cast<const uint4*>(&hu[(size_t)(b0 + row) * 256 + ch * 128 + c4 * 4]);
        }
        {
            const int row = t >> 5;         // 0..15
            const int c4  = t & 31;
            *reinterpret_cast<uint4*>(&ws[row][c4 * 4]) =
                *reinterpret_cast<const uint4*>(&wu[(size_t)(o0 + row) * 256 + ch * 128 + c4 * 4]);
        }
        __syncthreads();

        #pragma unroll
        for (int g = 0; g < 4; ++g) {   // 4 uint4-cols = 32 k per thread per chunk
            const int col = ks * 16 + g * 4;
            uint4 hv[4], wv[2];
            #pragma unroll
            for (int c = 0; c < 4; ++c)
                hv[c] = *reinterpret_cast<const uint4*>(&hs[bi + 8 * c][col]);
            #pragma unroll
            for (int d = 0; d < 2; ++d)
                wv[d] = *reinterpret_cast<const uint4*>(&ws[oj + 8 * d][col]);
            #pragma unroll
            for (int c = 0; c < 4; ++c) {
                #pragma unroll
                for (int d = 0; d < 2; ++d) {
                    canb2(hv[c].x, wv[d].x, acc[c][d], two);
                    canb2(hv[c].y, wv[d].y, acc[c][d], two);
                    canb2(hv[c].z, wv[d].z, acc[c][d], two);
                    canb2(hv[c].w, wv[d].w, acc[c][d], two);
                }
            }
        }
    }

    float p[8];
    #pragma unroll
    for (int c = 0; c < 4; ++c)
        #pragma unroll
        for (int d = 0; d < 2; ++d) {
            const half2v av = __builtin_bit_cast(half2v, acc[c][d]);
            p[c * 2 + d] = (float)av.x + (float)av.y;
        }

    // 8-way k-reduce, transposed conflict-free layout (r8-proven): bank = lane%32
    __syncthreads();
    float* red = reinterpret_cast<float*>(&hs[0][0]);   // [8][448] floats = 14.3 KB
    if (ks > 0) {
        const int slot = (ks - 1) * 64 + l;
        #pragma unroll
        for (int i = 0; i < 8; ++i) red[i * 448 + slot] = p[i];
    }
    __syncthreads();
    if (ks == 0) {
        #pragma unroll
        for (int q = 0; q < 7; ++q) {
            #pragma unroll
            for (int i = 0; i < 8; ++i) p[i] += red[i * 448 + q * 64 + l];
        }
        #pragma unroll
        for (int c = 0; c < 4; ++c) {
            #pragma unroll
            for (int d = 0; d < 2; ++d) {
                float dd = 512.0f - 2.0f * p[c * 2 + d] + EPSF;
                dd = fminf(fmaxf(dd, EPSF), 1000000.0f);
                out[(size_t)(b0 + bi + 8 * c) * OUT_SZ + o0 + oj + 8 * d] = 1.0f / dd;
            }
        }
    }
}

extern "C" void kernel_launch(void* const* d_in, const int* in_sizes, int n_in,
                              void* d_out, int out_size, void* d_ws, size_t ws_size,
                              hipStream_t stream) {
    const float* x  = (const float*)d_in[0];
    const float* W1 = (const float*)d_in[1];
    const float* b1 = (const float*)d_in[2];
    const float* Wd = (const float*)d_in[3];
    float* out = (float*)d_out;
    unsigned short* hh = (unsigned short*)d_ws;                          // 1 MB fp16 h
    unsigned short* wh = (unsigned short*)((char*)d_ws + (1u << 20));    // 0.5 MB fp16 relu(Wd)

    gemm10<<<dim3(32, 16), 512, 0, stream>>>(x, W1, b1, Wd, hh, wh);
    canberra6<<<dim3(32, 32), 512, 0, stream>>>(hh, wh, out);
}

// Round 13
// 32.033 us; speedup vs baseline: 2.8864x; 1.2251x over previous
//
#include <hip/hip_runtime.h>
#include <hip/hip_fp16.h>

#define DIN 1024
#define H_SZ 512
#define OUT_SZ 512
#define EPSF 1e-8f

typedef __attribute__((ext_vector_type(8))) short short8v;   // 8 bf16 = 4 VGPRs
typedef __attribute__((ext_vector_type(4))) float f32x4;
typedef _Float16 half2v __attribute__((ext_vector_type(2)));

// Canberra core v2: 4 packed ops per 2 terms (was 6 with Newton).
// term = min(h,w') * magicrcp(h+w'), magicrcp via y_bits = 0x7799 - x_bits
// (constant optimized for standalone use: balanced +-5% rel err; 0x7784 was an NR seed).
// Safety: sm <= 8 -> bits <= 0x4800 < 0x7799, no cross-half borrow; sm=0 -> mn=0 -> term=0;
// no overflow (y <= ~31k < f16 max; no 2-x*y intermediate).
static __device__ inline void canb2f(unsigned hu, unsigned wu, unsigned& a) {
    unsigned mn, sm, y;
    asm("v_pk_min_f16 %0, %1, %2" : "=v"(mn) : "v"(hu), "v"(wu));
    asm("v_pk_add_f16 %0, %1, %2" : "=v"(sm) : "v"(hu), "v"(wu));
    y = 0x77997799u - sm;                           // v_sub_u32, literal in src0
    asm("v_pk_fma_f16 %0, %1, %2, %0" : "+v"(a) : "v"(mn), "v"(y));
}

// pack 2 fp32 -> 2 bf16 in one op (gfx950; RNE)
static __device__ inline unsigned cvtpk(float lo, float hi) {
    unsigned u;
    asm("v_cvt_pk_bf16_f32 %0, %1, %2" : "=v"(u) : "v"(lo), "v"(hi));
    return u;
}

// ---------------- GEMM v10 (r12, unchanged): XCD-quadrant swizzle + depth-2 prefetch ----------------
__global__ __launch_bounds__(512, 4) void gemm10(const float* __restrict__ x,
                                                 const float* __restrict__ W1,
                                                 const float* __restrict__ b1,
                                                 const float* __restrict__ Wd,
                                                 unsigned short* __restrict__ hh,
                                                 unsigned short* __restrict__ wh) {
    __shared__ unsigned short As[2][2][32][72];   // [khalf][buf][m][k]
    __shared__ unsigned short Bs[2][2][32][72];
    __shared__ float red[4][64][4];
    const int t  = threadIdx.x;

    // bijective XCD swizzle: flat -> (xcd, idx) -> (b-tile, o-tile)
    const int flat = blockIdx.x + 32 * blockIdx.y;   // 0..511, dispatch order
    const int xcd  = flat & 7;
    const int idx  = flat >> 3;                      // 0..63 within XCD
    const int bt   = (xcd >> 1) * 8 + (idx & 7);     // b-tile 0..31
    const int ot   = (xcd & 1) * 8 + (idx >> 3);     // o-tile 0..15
    const int b0 = bt * 32;
    const int o0 = ot * 32;

    const int w  = t >> 6;
    const int l  = t & 63;
    const int q  = w & 3;
    const int kh = w >> 2;             // k-half 0/1
    const int m0 = (q >> 1) * 16;
    const int n0 = (q & 1) * 16;
    const int lr = l & 15;
    const int lk = (l >> 4) * 8;
    const int th = t & 255;
    const int ar = th >> 3;            // 0..31
    const int ko = (th & 7) * 8;       // 0..56

    f32x4 acc = {0.f, 0.f, 0.f, 0.f};
    const float* arow = &x [(size_t)(b0 + ar) * DIN + kh * 512 + ko];
    const float* brow = &W1[(size_t)(o0 + ar) * DIN + kh * 512 + ko];

    float4 pa0[2], pa1[2], pb0[2], pb1[2];   // depth-2 prefetch ring
    #pragma unroll
    for (int i = 0; i < 2; ++i) {
        pa0[i] = *reinterpret_cast<const float4*>(arow + i * 64);
        pa1[i] = *reinterpret_cast<const float4*>(arow + i * 64 + 4);
        pb0[i] = *reinterpret_cast<const float4*>(brow + i * 64);
        pb1[i] = *reinterpret_cast<const float4*>(brow + i * 64 + 4);
    }

    #pragma unroll
    for (int it = 0; it < 8; ++it) {
        const int sl  = it & 1;        // reg ring slot == LDS dbuf
        uint4 av, bv;
        av.x = cvtpk(pa0[sl].x, pa0[sl].y);
        av.y = cvtpk(pa0[sl].z, pa0[sl].w);
        av.z = cvtpk(pa1[sl].x, pa1[sl].y);
        av.w = cvtpk(pa1[sl].z, pa1[sl].w);
        bv.x = cvtpk(pb0[sl].x, pb0[sl].y);
        bv.y = cvtpk(pb0[sl].z, pb0[sl].w);
        bv.z = cvtpk(pb1[sl].x, pb1[sl].y);
        bv.w = cvtpk(pb1[sl].z, pb1[sl].w);
        *reinterpret_cast<uint4*>(&As[kh][sl][ar][ko]) = av;
        *reinterpret_cast<uint4*>(&Bs[kh][sl][ar][ko]) = bv;
        __syncthreads();   // dbuf safe (proven r5-r12)
        if (it + 2 < 8) {  // prefetch 2 iters ahead into the slot just consumed
            pa0[sl] = *reinterpret_cast<const float4*>(arow + (it + 2) * 64);
            pa1[sl] = *reinterpret_cast<const float4*>(arow + (it + 2) * 64 + 4);
            pb0[sl] = *reinterpret_cast<const float4*>(brow + (it + 2) * 64);
            pb1[sl] = *reinterpret_cast<const float4*>(brow + (it + 2) * 64 + 4);
        }
        #pragma unroll
        for (int s = 0; s < 2; ++s) {
            const short8v af = *reinterpret_cast<const short8v*>(&As[kh][sl][m0 + lr][s * 32 + lk]);
            const short8v bf = *reinterpret_cast<const short8v*>(&Bs[kh][sl][n0 + lr][s * 32 + lk]);
            acc = __builtin_amdgcn_mfma_f32_16x16x32_bf16(af, bf, acc, 0, 0, 0);
        }
    }
    __syncthreads();
    if (kh == 1) {
        #pragma unroll
        for (int r = 0; r < 4; ++r) red[q][l][r] = acc[r];
    }
    __syncthreads();
    if (kh == 0) {
        // C/D layout (m89-verified): col = lane&15, row = (lane>>4)*4 + reg
        const int col = o0 + n0 + lr;
        const float bias = b1[col];
        #pragma unroll
        for (int r = 0; r < 4; ++r) {
            const float v = acc[r] + red[q][l][r] + bias;
            const int m = b0 + m0 + (l >> 4) * 4 + r;
            hh[(size_t)m * H_SZ + col] = __half_as_ushort(__float2half(fmaxf(v, 0.0f)));
        }
    }
    // Wd preprocess: 262144 elems == 512 blocks * 512 thr (flat covers 0..511 bijectively).
    const int gid = flat * 512 + t;
    const float wv0 = Wd[gid];
    wh[gid] = __half_as_ushort(__float2half(wv0 > 0.f ? wv0 : 0.f));
}

// ---------------- Canberra v7: r9 structure, 4-op inner (dropped Newton) ----------------
__global__ __launch_bounds__(512, 8) void canberra7(const unsigned short* __restrict__ hh,
                                                    const unsigned short* __restrict__ wh,
                                                    float* __restrict__ out) {
    __shared__ unsigned hs[32][132];   // 32 b-rows x 128 uints (256 k) + pad 4
    __shared__ unsigned ws[16][132];   // 16 o-rows x 128 uints + pad 4
    const int t  = threadIdx.x;
    const int b0 = blockIdx.x * 32;
    const int o0 = blockIdx.y * 16;
    const unsigned* hu = reinterpret_cast<const unsigned*>(hh);
    const unsigned* wu = reinterpret_cast<const unsigned*>(wh);

    const int ks = t >> 6;     // 0..7, wave-uniform k-slice
    const int l  = t & 63;
    const int bi = l >> 3;     // 0..7
    const int oj = l & 7;      // 0..7

    unsigned acc[4][2] = {};

    for (int ch = 0; ch < 2; ++ch) {    // two 256-k chunks
        if (ch) __syncthreads();        // previous chunk's reads complete
        #pragma unroll
        for (int r = 0; r < 2; ++r) {
            const int s = t + r * 512;
            const int row = s >> 5;         // 0..31
            const int c4  = s & 31;         // uint4 col
            *reinterpret_cast<uint4*>(&hs[row][c4 * 4]) =
                *reinterpret_cast<const uint4*>(&hu[(size_t)(b0 + row) * 256 + ch * 128 + c4 * 4]);
        }
        {
            const int row = t >> 5;         // 0..15
            const int c4  = t & 31;
            *reinterpret_cast<uint4*>(&ws[row][c4 * 4]) =
                *reinterpret_cast<const uint4*>(&wu[(size_t)(o0 + row) * 256 + ch * 128 + c4 * 4]);
        }
        __syncthreads();

        #pragma unroll
        for (int g = 0; g < 4; ++g) {   // 4 uint4-cols = 32 k per thread per chunk
            const int col = ks * 16 + g * 4;
            uint4 hv[4], wv[2];
            #pragma unroll
            for (int c = 0; c < 4; ++c)
                hv[c] = *reinterpret_cast<const uint4*>(&hs[bi + 8 * c][col]);
            #pragma unroll
            for (int d = 0; d < 2; ++d)
                wv[d] = *reinterpret_cast<const uint4*>(&ws[oj + 8 * d][col]);
            #pragma unroll
            for (int c = 0; c < 4; ++c) {
                #pragma unroll
                for (int d = 0; d < 2; ++d) {
                    canb2f(hv[c].x, wv[d].x, acc[c][d]);
                    canb2f(hv[c].y, wv[d].y, acc[c][d]);
                    canb2f(hv[c].z, wv[d].z, acc[c][d]);
                    canb2f(hv[c].w, wv[d].w, acc[c][d]);
                }
            }
        }
    }

    float p[8];
    #pragma unroll
    for (int c = 0; c < 4; ++c)
        #pragma unroll
        for (int d = 0; d < 2; ++d) {
            const half2v av = __builtin_bit_cast(half2v, acc[c][d]);
            p[c * 2 + d] = (float)av.x + (float)av.y;
        }

    // 8-way k-reduce, transposed conflict-free layout (r8-proven): bank = lane%32
    __syncthreads();
    float* red = reinterpret_cast<float*>(&hs[0][0]);   // [8][448] floats = 14.3 KB
    if (ks > 0) {
        const int slot = (ks - 1) * 64 + l;
        #pragma unroll
        for (int i = 0; i < 8; ++i) red[i * 448 + slot] = p[i];
    }
    __syncthreads();
    if (ks == 0) {
        #pragma unroll
        for (int q = 0; q < 7; ++q) {
            #pragma unroll
            for (int i = 0; i < 8; ++i) p[i] += red[i * 448 + q * 64 + l];
        }
        #pragma unroll
        for (int c = 0; c < 4; ++c) {
            #pragma unroll
            for (int d = 0; d < 2; ++d) {
                float dd = 512.0f - 2.0f * p[c * 2 + d] + EPSF;
                dd = fminf(fmaxf(dd, EPSF), 1000000.0f);
                out[(size_t)(b0 + bi + 8 * c) * OUT_SZ + o0 + oj + 8 * d] = 1.0f / dd;
            }
        }
    }
}

extern "C" void kernel_launch(void* const* d_in, const int* in_sizes, int n_in,
                              void* d_out, int out_size, void* d_ws, size_t ws_size,
                              hipStream_t stream) {
    const float* x  = (const float*)d_in[0];
    const float* W1 = (const float*)d_in[1];
    const float* b1 = (const float*)d_in[2];
    const float* Wd = (const float*)d_in[3];
    float* out = (float*)d_out;
    unsigned short* hh = (unsigned short*)d_ws;                          // 1 MB fp16 h
    unsigned short* wh = (unsigned short*)((char*)d_ws + (1u << 20));    // 0.5 MB fp16 relu(Wd)

    gemm10<<<dim3(32, 16), 512, 0, stream>>>(x, W1, b1, Wd, hh, wh);
    canberra7<<<dim3(32, 32), 512, 0, stream>>>(hh, wh, out);
}